// Round 4
// baseline (302.002 us; speedup 1.0000x reference)
//
#include <hip/hip_runtime.h>

#define L_DIM 1024
#define B_DIM 16
#define D_DIM 1024
#define K_DIM 1024            // = D
#define N_DIM 3072            // = 3*D
#define M_DIM (L_DIM * B_DIM) // 16384
#define CHAINS 16384          // B*D
#define CHUNK 32              // steps per chunk
#define NCHUNK 32             // L / CHUNK

typedef float f32x4 __attribute__((ext_vector_type(4)));
typedef __bf16 bf16x8 __attribute__((ext_vector_type(8)));
typedef unsigned short u16;
typedef unsigned int u32;

__device__ __forceinline__ u16 f2bf(float f) {
  u32 u = __float_as_uint(f);
  u = u + 0x7FFFu + ((u >> 16) & 1u);   // round-to-nearest-even
  return (u16)(u >> 16);
}
__device__ __forceinline__ float bf2f(u16 v) {
  return __uint_as_float(((u32)v) << 16);
}
__device__ __forceinline__ float bf2f_lo(u32 v) {
  return __uint_as_float(v << 16);
}
__device__ __forceinline__ float bf2f_hi(u32 v) {
  return __uint_as_float(v & 0xffff0000u);
}
__device__ __forceinline__ float fexp(float v) {
  return __builtin_amdgcn_exp2f(v * 1.4426950408889634f);
}
__device__ __forceinline__ float sigm(float z) {
  return __builtin_amdgcn_rcpf(1.0f + fexp(-z));
}
__device__ __forceinline__ float ftanh(float v) {
  return 1.0f - 2.0f * __builtin_amdgcn_rcpf(1.0f + fexp(2.0f * v));
}
__device__ __forceinline__ uint4 pack8(f32x4 a, f32x4 b) {
  uint4 r;
  r.x = (u32)f2bf(a[0]) | ((u32)f2bf(a[1]) << 16);
  r.y = (u32)f2bf(a[2]) | ((u32)f2bf(a[3]) << 16);
  r.z = (u32)f2bf(b[0]) | ((u32)f2bf(b[1]) << 16);
  r.w = (u32)f2bf(b[2]) | ((u32)f2bf(b[3]) << 16);
  return r;
}

// ---------------- W (K x N fp32) -> Wt (N' x K bf16), plane-major N permute ----------------
__global__ __launch_bounds__(256) void cvt_w_kernel(const float* __restrict__ W,
                                                    u16* __restrict__ Wt) {
  __shared__ float tile[64][65];
  int c0 = blockIdx.x * 64;  // N block
  int r0 = blockIdx.y * 64;  // K block
  int tx = threadIdx.x & 63;
  int ty = threadIdx.x >> 6;
#pragma unroll
  for (int i = 0; i < 16; ++i) {
    int row = i * 4 + ty;
    tile[row][tx] = W[(size_t)(r0 + row) * N_DIM + c0 + tx];
  }
  __syncthreads();
#pragma unroll
  for (int i = 0; i < 16; ++i) {
    int crow = i * 4 + ty;
    int c = c0 + crow;
    int nprime = (c % 3) * D_DIM + (c / 3);
    Wt[(size_t)nprime * K_DIM + r0 + tx] = f2bf(tile[tx][crow]);
  }
}

// ---------------- GEMM: 256x256 tile, BK=64, 8-phase counted-vmcnt schedule ----------------
// A is read directly from x (fp32) via reg-staging (T14): loads issued in phases 1-2,
// RNE-convert + ds_write in phase 4 after the counted vmcnt. B stays global_load_lds.
// Per iter: A = 8 global_load_dwordx4, B = 4 global_load_lds. At phase-4 vmcnt point
// outstanding = prevB(4) + A(8) + curB(4) = 16; vmcnt(4) retires prevB+A, leaves curB.

#define AS1 __attribute__((address_space(1)))
#define AS3 __attribute__((address_space(3)))
#define STAGE(gp, lp) do { \
  __builtin_amdgcn_global_load_lds((const AS1 void*)(gp), (AS3 void*)(lp), 16, 0, 0); \
  __builtin_amdgcn_global_load_lds((const AS1 void*)((gp) + (size_t)64 * K_DIM), \
                                   (AS3 void*)((lp) + 4096), 16, 0, 0); \
} while (0)

#define QUAD(AI, JB, BF) \
  _Pragma("unroll") \
  for (int i = 0; i < 4; ++i) { \
    _Pragma("unroll") \
    for (int j = 0; j < 2; ++j) { \
      acc[AI + i][JB + j] = __builtin_amdgcn_mfma_f32_16x16x32_bf16(aF[i][0], BF[j][0], acc[AI + i][JB + j], 0, 0, 0); \
      acc[AI + i][JB + j] = __builtin_amdgcn_mfma_f32_16x16x32_bf16(aF[i][1], BF[j][1], acc[AI + i][JB + j], 0, 0, 0); \
    } \
  }

__global__ __launch_bounds__(512, 2) void gemm_kernel(const float* __restrict__ X,
                                                      const u16* __restrict__ Bt,
                                                      u16* __restrict__ U) {
  __shared__ __align__(16) u16 sm[65536];   // 128 KiB
  const int tid = threadIdx.x;
  const int wave = tid >> 6;
  const int lane = tid & 63;
  const int wm = wave >> 2;        // 0..1  (M)
  const int wn = wave & 3;         // 0..3  (N)
  const int quad = lane >> 4;
  const int l16 = lane & 15;

  // XCD-aware bijective swizzle: 768 blocks, 96 per XCD = 8 contiguous M-rows x 12 N.
  const int flat = blockIdx.y * 12 + blockIdx.x;
  const int swz = (flat & 7) * 96 + (flat >> 3);
  const int m0 = (swz / 12) * 256;
  const int n0 = (swz % 12) * 256;

  // staging addressing: thread t covers HT rows rr and rr+64, 16 B each,
  // global k-slot pre-swizzled so linear LDS dest yields swizzled content.
  const int rr = tid >> 3;                      // 0..63
  const int slot = (tid & 7) ^ (rr & 7);
  const float* gA = X + (size_t)(m0 + rr) * K_DIM + slot * 8;   // fp32 source
  const u16* gB = Bt + (size_t)(n0 + rr) * K_DIM + slot * 8;

  u16* ldsB = sm + 32768 + wave * 512;          // gload_lds base (HW adds lane*16B)
  u16* wrA = sm + tid * 8;                      // per-thread linear A dest (u16)

  // fragment read bases (swizzled column offsets)
  const int swzu = (l16 & 7) << 3;              // u16 units
  const int c0 = (quad * 8) ^ swzu;             // ks=0
  const int c1 = (32 + quad * 8) ^ swzu;        // ks=1
  const u16* pA = sm + (wm * 128 + l16) * 64;
  const u16* pB = sm + 32768 + (wn * 64 + l16) * 64;

  f32x4 acc[8][4] = {};

  // prologue: A kt0 via regs; B kt0 + kt1 via gload_lds; leave B kt1 in flight
  {
    f32x4 a0 = *(const f32x4*)(gA);
    f32x4 a1 = *(const f32x4*)(gA + 4);
    f32x4 a2 = *(const f32x4*)(gA + (size_t)64 * K_DIM);
    f32x4 a3 = *(const f32x4*)(gA + (size_t)64 * K_DIM + 4);
    f32x4 a4 = *(const f32x4*)(gA + (size_t)128 * K_DIM);
    f32x4 a5 = *(const f32x4*)(gA + (size_t)128 * K_DIM + 4);
    f32x4 a6 = *(const f32x4*)(gA + (size_t)192 * K_DIM);
    f32x4 a7 = *(const f32x4*)(gA + (size_t)192 * K_DIM + 4);
    STAGE(gB, ldsB);                                   // B kt0 HT0
    STAGE(gB + (size_t)128 * K_DIM, ldsB + 8192);      // B kt0 HT1
    STAGE(gB + 64, ldsB + 16384);                      // B kt1 HT0
    STAGE(gB + (size_t)128 * K_DIM + 64, ldsB + 16384 + 8192); // B kt1 HT1
    asm volatile("s_waitcnt vmcnt(8)" ::: "memory");   // retire the 8 A loads
    *(uint4*)(wrA)              = pack8(a0, a1);
    *(uint4*)(wrA + 4096)       = pack8(a2, a3);
    *(uint4*)(wrA + 8192)       = pack8(a4, a5);
    *(uint4*)(wrA + 8192 + 4096) = pack8(a6, a7);
    asm volatile("s_waitcnt vmcnt(4) lgkmcnt(0)" ::: "memory"); // B kt0 in LDS; kt1 in flight
  }
  __builtin_amdgcn_s_barrier();

  for (int u = 0; u < 16; ++u) {
    const int buf = u & 1;
    const int nb = buf ^ 1;
    const u16* pAb = pA + buf * 16384;
    const u16* pBb = pB + buf * 16384;
    bf16x8 aF[4][2], bLo[2][2], bHi[2][2];
    f32x4 n0a, n0b, n1a, n1b, n2a, n2b, n3a, n3b;

    // ---- phase 1: Q(0,0)  [reads A mt0-3 + B nt0-1; load A-HT0[u+1] to regs] ----
#pragma unroll
    for (int i = 0; i < 4; ++i) {
      aF[i][0] = *(const bf16x8*)(pAb + i * 1024 + c0);
      aF[i][1] = *(const bf16x8*)(pAb + i * 1024 + c1);
    }
#pragma unroll
    for (int j = 0; j < 2; ++j) {
      bLo[j][0] = *(const bf16x8*)(pBb + j * 1024 + c0);
      bLo[j][1] = *(const bf16x8*)(pBb + j * 1024 + c1);
    }
    if (u < 15) {
      n0a = *(const f32x4*)(gA + (u + 1) * 64);
      n0b = *(const f32x4*)(gA + (u + 1) * 64 + 4);
      n1a = *(const f32x4*)(gA + (size_t)64 * K_DIM + (u + 1) * 64);
      n1b = *(const f32x4*)(gA + (size_t)64 * K_DIM + (u + 1) * 64 + 4);
    }
    __builtin_amdgcn_s_barrier();
    __builtin_amdgcn_s_setprio(1);
    QUAD(0, 0, bLo)
    __builtin_amdgcn_s_setprio(0);
    __builtin_amdgcn_s_barrier();

    // ---- phase 2: Q(0,1)  [reads B nt2-3; load A-HT1[u+1] to regs] ----
#pragma unroll
    for (int j = 0; j < 2; ++j) {
      bHi[j][0] = *(const bf16x8*)(pBb + (2 + j) * 1024 + c0);
      bHi[j][1] = *(const bf16x8*)(pBb + (2 + j) * 1024 + c1);
    }
    if (u < 15) {
      n2a = *(const f32x4*)(gA + (size_t)128 * K_DIM + (u + 1) * 64);
      n2b = *(const f32x4*)(gA + (size_t)128 * K_DIM + (u + 1) * 64 + 4);
      n3a = *(const f32x4*)(gA + (size_t)192 * K_DIM + (u + 1) * 64);
      n3b = *(const f32x4*)(gA + (size_t)192 * K_DIM + (u + 1) * 64 + 4);
    }
    __builtin_amdgcn_s_barrier();
    __builtin_amdgcn_s_setprio(1);
    QUAD(0, 2, bHi)
    __builtin_amdgcn_s_setprio(0);
    __builtin_amdgcn_s_barrier();

    // ---- phase 3: Q(1,1)  [reads A mt4-7; stage B-HT0[u+2]] ----
#pragma unroll
    for (int i = 0; i < 4; ++i) {
      aF[i][0] = *(const bf16x8*)(pAb + (4 + i) * 1024 + c0);
      aF[i][1] = *(const bf16x8*)(pAb + (4 + i) * 1024 + c1);
    }
    if (u < 14) STAGE(gB + (u + 2) * 64, ldsB + buf * 16384);
    __builtin_amdgcn_s_barrier();
    __builtin_amdgcn_s_setprio(1);
    QUAD(4, 2, bHi)
    __builtin_amdgcn_s_setprio(0);
    __builtin_amdgcn_s_barrier();

    // ---- phase 4: Q(1,0)  [stage B-HT1[u+2]; counted vmcnt; cvt+write A[u+1]] ----
    if (u < 14) {
      STAGE(gB + (size_t)128 * K_DIM + (u + 2) * 64, ldsB + buf * 16384 + 8192);
      asm volatile("s_waitcnt vmcnt(4)" ::: "memory");
    } else if (u == 14) {
      asm volatile("s_waitcnt vmcnt(0)" ::: "memory");
    }
    if (u < 15) {
      u16* wA = wrA + nb * 16384;
      *(uint4*)(wA)              = pack8(n0a, n0b);
      *(uint4*)(wA + 4096)       = pack8(n1a, n1b);
      *(uint4*)(wA + 8192)       = pack8(n2a, n2b);
      *(uint4*)(wA + 8192 + 4096) = pack8(n3a, n3b);
      asm volatile("s_waitcnt lgkmcnt(0)" ::: "memory");
    }
    __builtin_amdgcn_s_barrier();
    __builtin_amdgcn_s_setprio(1);
    QUAD(4, 0, bLo)
    __builtin_amdgcn_s_setprio(0);
    __builtin_amdgcn_s_barrier();
  }

  // epilogue: C/D layout col=lane&15, row=(lane>>4)*4+r
#pragma unroll
  for (int i = 0; i < 8; ++i) {
#pragma unroll
    for (int j = 0; j < 4; ++j) {
      const int col = n0 + wn * 64 + j * 16 + l16;
      const int rb = m0 + wm * 128 + i * 16 + quad * 4;
#pragma unroll
      for (int r = 0; r < 4; ++r)
        U[(size_t)(rb + r) * N_DIM + col] = f2bf(acc[i][j][r]);
    }
  }
}

// ---------------- SRU fused scan: full-line blocks ----------------
// 256 blocks x 1024 threads; block owns 64 consecutive chains (one b, 64 d) = one full
// 128-B line per U-plane row. Threads = (32 pairs) x (32 chunks); lanes 0-31 of each
// wave read one contiguous 128-B line per plane. Compositions -> LDS; 64-lane serial
// scan; replay. XCD-bijective swizzle over 256 blocks (8 x 32).

__global__ __launch_bounds__(1024) void sru_fused(const u16* __restrict__ U,
                                                  const float* __restrict__ x,
                                                  const float* __restrict__ bias,
                                                  const float* __restrict__ c0,
                                                  float* __restrict__ h,
                                                  float* __restrict__ clast) {
  __shared__ float sA[NCHUNK][64];
  __shared__ float sB[NCHUNK][64];
  __shared__ float sC[NCHUNK][64];

  const int flat = blockIdx.x;                     // 0..255
  const int cb = (flat & 7) * 32 + (flat >> 3);    // chain-block 0..255
  const int b  = cb >> 4;                          // batch 0..15
  const int d0 = (cb & 15) << 6;                   // d base, step 64
  const int t  = threadIdx.x;
  const int pr = t & 31;                           // pair 0..31
  const int j  = t >> 5;                           // chunk 0..31
  const int d2 = d0 + pr * 2;

  const float2 bb1 = *(const float2*)(bias + d2);

  // ---- phase A: per-(chunk, chain-pair) affine composition ----
  {
    const u16* p = U + (size_t)(j * CHUNK * B_DIM + b) * N_DIM + d2;
    float A0 = 1.0f, A1 = 1.0f, B0 = 0.0f, B1 = 0.0f;
#pragma unroll 4
    for (int s = 0; s < CHUNK; ++s) {
      u32 w0 = *(const u32*)p;
      u32 w1 = *(const u32*)(p + D_DIM);
      float u0a = bf2f_lo(w0), u0b = bf2f_hi(w0);
      float g1a = sigm(bf2f_lo(w1) + bb1.x);
      float g1b = sigm(bf2f_hi(w1) + bb1.y);
      B0 = (B0 - u0a) * g1a + u0a;
      B1 = (B1 - u0b) * g1b + u0b;
      A0 *= g1a;
      A1 *= g1b;
      p += (size_t)B_DIM * N_DIM;
    }
    *(float2*)&sA[j][pr * 2] = make_float2(A0, A1);
    *(float2*)&sB[j][pr * 2] = make_float2(B0, B1);
  }
  __syncthreads();

  // ---- phase B: serial scan over 32 chunks, one lane per chain ----
  if (t < 64) {
    const int chain = cb * 64 + t;   // = b*D + d0 + t
    float c = c0[chain];
#pragma unroll
    for (int jj = 0; jj < NCHUNK; ++jj) {
      sC[jj][t] = c;
      c = sA[jj][t] * c + sB[jj][t];
    }
    clast[chain] = c;
  }
  __syncthreads();

  // ---- phase C: replay with h output ----
  {
    const float2 bb2 = *(const float2*)(bias + D_DIM + d2);
    float2 c = *(const float2*)&sC[j][pr * 2];
    const size_t m0 = (size_t)(j * CHUNK * B_DIM + b);
    const u16* p = U + m0 * N_DIM + d2;
    const float* xp = x + m0 * D_DIM + d2;
    float* hp = h + m0 * D_DIM + d2;
#pragma unroll 4
    for (int s = 0; s < CHUNK; ++s) {
      u32 w0 = *(const u32*)p;
      u32 w1 = *(const u32*)(p + D_DIM);
      u32 w2 = *(const u32*)(p + 2 * D_DIM);
      float2 xv = *(const float2*)xp;
      float u0a = bf2f_lo(w0), u0b = bf2f_hi(w0);
      float g1a = sigm(bf2f_lo(w1) + bb1.x);
      float g1b = sigm(bf2f_hi(w1) + bb1.y);
      float g2a = sigm(bf2f_lo(w2) + bb2.x);
      float g2b = sigm(bf2f_hi(w2) + bb2.y);
      c.x = (c.x - u0a) * g1a + u0a;
      c.y = (c.y - u0b) * g1b + u0b;
      float2 hv;
      hv.x = (ftanh(c.x) - xv.x) * g2a + xv.x;
      hv.y = (ftanh(c.y) - xv.y) * g2b + xv.y;
      *(float2*)hp = hv;
      p += (size_t)B_DIM * N_DIM;
      xp += B_DIM * D_DIM;
      hp += B_DIM * D_DIM;
    }
  }
}

extern "C" void kernel_launch(void* const* d_in, const int* in_sizes, int n_in,
                              void* d_out, int out_size, void* d_ws, size_t ws_size,
                              hipStream_t stream) {
  const float* x = (const float*)d_in[0];     // L*B*D
  const float* W = (const float*)d_in[1];     // K x 3D
  const float* bias = (const float*)d_in[2];  // 2D
  const float* c0 = (const float*)d_in[3];    // B*D
  float* out = (float*)d_out;

  char* ws = (char*)d_ws;
  u16* wt = (u16*)ws;                               // 6 MiB
  u16* U = (u16*)(ws + 8388608);                    // 96 MiB

  cvt_w_kernel<<<dim3(48, 16), 256, 0, stream>>>(W, wt);
  gemm_kernel<<<dim3(N_DIM / 256, M_DIM / 256), 512, 0, stream>>>(x, wt, U);
  sru_fused<<<256, 1024, 0, stream>>>(U, x, bias, c0, out, out + (size_t)M_DIM * D_DIM);
}

// Round 5
// 270.890 us; speedup vs baseline: 1.1149x; 1.1149x over previous
//
#include <hip/hip_runtime.h>

#define L_DIM 1024
#define B_DIM 16
#define D_DIM 1024
#define K_DIM 1024            // = D
#define N_DIM 3072            // = 3*D
#define M_DIM (L_DIM * B_DIM) // 16384
#define CHAINS 16384          // B*D
#define CHUNK 16              // steps per chunk
#define NCHUNK 64             // L / CHUNK

typedef float f32x4 __attribute__((ext_vector_type(4)));
typedef __bf16 bf16x8 __attribute__((ext_vector_type(8)));
typedef unsigned short u16;
typedef unsigned int u32;

__device__ __forceinline__ u16 f2bf(float f) {
  u32 u = __float_as_uint(f);
  u = u + 0x7FFFu + ((u >> 16) & 1u);   // round-to-nearest-even
  return (u16)(u >> 16);
}
__device__ __forceinline__ float bf2f(u16 v) {
  return __uint_as_float(((u32)v) << 16);
}
__device__ __forceinline__ float bf2f_lo(u32 v) {
  return __uint_as_float(v << 16);
}
__device__ __forceinline__ float bf2f_hi(u32 v) {
  return __uint_as_float(v & 0xffff0000u);
}
__device__ __forceinline__ float fexp(float v) {
  return __builtin_amdgcn_exp2f(v * 1.4426950408889634f);
}
__device__ __forceinline__ float sigm(float z) {
  return __builtin_amdgcn_rcpf(1.0f + fexp(-z));
}
__device__ __forceinline__ float ftanh(float v) {
  return 1.0f - 2.0f * __builtin_amdgcn_rcpf(1.0f + fexp(2.0f * v));
}

// ---------------- x: fp32 -> bf16 straight cast ----------------
__global__ __launch_bounds__(256) void cvt_x_kernel(const float4* __restrict__ in,
                                                    ushort4* __restrict__ out, int n4) {
  int i = blockIdx.x * 256 + threadIdx.x;
  if (i < n4) {
    float4 v = in[i];
    ushort4 o;
    o.x = f2bf(v.x); o.y = f2bf(v.y); o.z = f2bf(v.z); o.w = f2bf(v.w);
    out[i] = o;
  }
}

// ---------------- W (K x N fp32) -> Wt (N' x K bf16), plane-major N permute ----------------
__global__ __launch_bounds__(256) void cvt_w_kernel(const float* __restrict__ W,
                                                    u16* __restrict__ Wt) {
  __shared__ float tile[64][65];
  int c0 = blockIdx.x * 64;  // N block
  int r0 = blockIdx.y * 64;  // K block
  int tx = threadIdx.x & 63;
  int ty = threadIdx.x >> 6;
#pragma unroll
  for (int i = 0; i < 16; ++i) {
    int row = i * 4 + ty;
    tile[row][tx] = W[(size_t)(r0 + row) * N_DIM + c0 + tx];
  }
  __syncthreads();
#pragma unroll
  for (int i = 0; i < 16; ++i) {
    int crow = i * 4 + ty;
    int c = c0 + crow;
    int nprime = (c % 3) * D_DIM + (c / 3);
    Wt[(size_t)nprime * K_DIM + r0 + tx] = f2bf(tile[tx][crow]);
  }
}

// ---------------- GEMM: 256x256 tile, BK=64, 8-phase counted-vmcnt schedule ----------------
// (round-1 version restored verbatim — 106-110 us, MfmaUtil ~40%, bank conflicts 0)

#define AS1 __attribute__((address_space(1)))
#define AS3 __attribute__((address_space(3)))
#define STAGE(gp, lp) do { \
  __builtin_amdgcn_global_load_lds((const AS1 void*)(gp), (AS3 void*)(lp), 16, 0, 0); \
  __builtin_amdgcn_global_load_lds((const AS1 void*)((gp) + (size_t)64 * K_DIM), \
                                   (AS3 void*)((lp) + 4096), 16, 0, 0); \
} while (0)

#define QUAD(AI, JB, BF) \
  _Pragma("unroll") \
  for (int i = 0; i < 4; ++i) { \
    _Pragma("unroll") \
    for (int j = 0; j < 2; ++j) { \
      acc[AI + i][JB + j] = __builtin_amdgcn_mfma_f32_16x16x32_bf16(aF[i][0], BF[j][0], acc[AI + i][JB + j], 0, 0, 0); \
      acc[AI + i][JB + j] = __builtin_amdgcn_mfma_f32_16x16x32_bf16(aF[i][1], BF[j][1], acc[AI + i][JB + j], 0, 0, 0); \
    } \
  }

__global__ __launch_bounds__(512, 2) void gemm_kernel(const u16* __restrict__ A,
                                                      const u16* __restrict__ Bt,
                                                      u16* __restrict__ U) {
  __shared__ __align__(16) u16 sm[65536];   // 128 KiB
  const int tid = threadIdx.x;
  const int wave = tid >> 6;
  const int lane = tid & 63;
  const int wm = wave >> 2;        // 0..1  (M)
  const int wn = wave & 3;         // 0..3  (N)
  const int quad = lane >> 4;
  const int l16 = lane & 15;

  // XCD-aware bijective swizzle: 768 blocks, 96 per XCD = 8 contiguous M-rows x 12 N.
  const int flat = blockIdx.y * 12 + blockIdx.x;
  const int swz = (flat & 7) * 96 + (flat >> 3);
  const int m0 = (swz / 12) * 256;
  const int n0 = (swz % 12) * 256;

  // staging source (per-thread): thread t covers HT rows rr and rr+64, 16 B each,
  // global k-slot pre-swizzled so linear LDS dest yields swizzled content.
  const int rr = tid >> 3;                      // 0..63
  const int slot = (tid & 7) ^ (rr & 7);
  const u16* gA = A + (size_t)(m0 + rr) * K_DIM + slot * 8;
  const u16* gB = Bt + (size_t)(n0 + rr) * K_DIM + slot * 8;

  // LDS stage dest bases (u16 units); HW adds lane*16 B.
  u16* ldsA = sm + wave * 512;
  u16* ldsB = sm + 32768 + wave * 512;

  // fragment read bases (swizzled column offsets)
  const int swzu = (l16 & 7) << 3;              // u16 units
  const int c0 = (quad * 8) ^ swzu;             // ks=0
  const int c1 = (32 + quad * 8) ^ swzu;        // ks=1
  const u16* pA = sm + (wm * 128 + l16) * 64;
  const u16* pB = sm + 32768 + (wn * 64 + l16) * 64;

  f32x4 acc[8][4] = {};

  // prologue: K-tile 0 fully -> buf0; B half-tiles of K-tile 1 -> buf1
  STAGE(gA, ldsA);                                   // A kt0 HT0
  STAGE(gA + (size_t)128 * K_DIM, ldsA + 8192);      // A kt0 HT1
  STAGE(gB, ldsB);                                   // B kt0 HT0
  STAGE(gB + (size_t)128 * K_DIM, ldsB + 8192);      // B kt0 HT1
  STAGE(gB + 64, ldsB + 16384);                      // B kt1 HT0
  STAGE(gB + (size_t)128 * K_DIM + 64, ldsB + 16384 + 8192); // B kt1 HT1
  asm volatile("s_waitcnt vmcnt(0)" ::: "memory");
  __builtin_amdgcn_s_barrier();

  for (int u = 0; u < 16; ++u) {
    const int buf = u & 1;
    const int nb = buf ^ 1;
    const u16* pAb = pA + buf * 16384;
    const u16* pBb = pB + buf * 16384;
    bf16x8 aF[4][2], bLo[2][2], bHi[2][2];

    // ---- phase 1: Q(0,0)  [reads A mt0-3 + B nt0-1; stage A-HT0[u+1]] ----
#pragma unroll
    for (int i = 0; i < 4; ++i) {
      aF[i][0] = *(const bf16x8*)(pAb + i * 1024 + c0);
      aF[i][1] = *(const bf16x8*)(pAb + i * 1024 + c1);
    }
#pragma unroll
    for (int j = 0; j < 2; ++j) {
      bLo[j][0] = *(const bf16x8*)(pBb + j * 1024 + c0);
      bLo[j][1] = *(const bf16x8*)(pBb + j * 1024 + c1);
    }
    if (u < 15) STAGE(gA + (u + 1) * 64, ldsA + nb * 16384);
    __builtin_amdgcn_s_barrier();
    __builtin_amdgcn_s_setprio(1);
    QUAD(0, 0, bLo)
    __builtin_amdgcn_s_setprio(0);
    __builtin_amdgcn_s_barrier();

    // ---- phase 2: Q(0,1)  [reads B nt2-3; stage A-HT1[u+1]] ----
#pragma unroll
    for (int j = 0; j < 2; ++j) {
      bHi[j][0] = *(const bf16x8*)(pBb + (2 + j) * 1024 + c0);
      bHi[j][1] = *(const bf16x8*)(pBb + (2 + j) * 1024 + c1);
    }
    if (u < 15) STAGE(gA + (size_t)128 * K_DIM + (u + 1) * 64, ldsA + nb * 16384 + 8192);
    __builtin_amdgcn_s_barrier();
    __builtin_amdgcn_s_setprio(1);
    QUAD(0, 2, bHi)
    __builtin_amdgcn_s_setprio(0);
    __builtin_amdgcn_s_barrier();

    // ---- phase 3: Q(1,1)  [reads A mt4-7; stage B-HT0[u+2]] ----
#pragma unroll
    for (int i = 0; i < 4; ++i) {
      aF[i][0] = *(const bf16x8*)(pAb + (4 + i) * 1024 + c0);
      aF[i][1] = *(const bf16x8*)(pAb + (4 + i) * 1024 + c1);
    }
    if (u < 14) STAGE(gB + (u + 2) * 64, ldsB + buf * 16384);
    __builtin_amdgcn_s_barrier();
    __builtin_amdgcn_s_setprio(1);
    QUAD(4, 2, bHi)
    __builtin_amdgcn_s_setprio(0);
    __builtin_amdgcn_s_barrier();

    // ---- phase 4: Q(1,0)  [stage B-HT1[u+2]; counted vmcnt] ----
    if (u < 14) {
      STAGE(gB + (size_t)128 * K_DIM + (u + 2) * 64, ldsB + buf * 16384 + 8192);
      asm volatile("s_waitcnt vmcnt(4)" ::: "memory");
    } else if (u == 14) {
      asm volatile("s_waitcnt vmcnt(0)" ::: "memory");
    }
    __builtin_amdgcn_s_barrier();
    __builtin_amdgcn_s_setprio(1);
    QUAD(4, 0, bLo)
    __builtin_amdgcn_s_setprio(0);
    __builtin_amdgcn_s_barrier();
  }

  // epilogue: C/D layout col=lane&15, row=(lane>>4)*4+r
#pragma unroll
  for (int i = 0; i < 8; ++i) {
#pragma unroll
    for (int j = 0; j < 4; ++j) {
      const int col = n0 + wn * 64 + j * 16 + l16;
      const int rb = m0 + wm * 128 + i * 16 + quad * 4;
#pragma unroll
      for (int r = 0; r < 4; ++r)
        U[(size_t)(rb + r) * N_DIM + col] = f2bf(acc[i][j][r]);
    }
  }
}

// ---------------- SRU fused scan: full-line blocks, 4 chains/thread ----------------
// 256 blocks x 1024 threads; block owns 64 consecutive chains (one b, 64 d) = one full
// 128-B line per U-plane row. Threads = (16 quads of 4 chains) x (64 chunks of 16 steps).
// Per wave-load: 16 lanes x 8 B = one full line per chunk-row, 4 chunks/wave = 512 B.
// Compositions -> LDS; 64-lane serial scan; replay. XCD-bijective swizzle (256 = 8x32).

__global__ __launch_bounds__(1024) void sru_fused(const u16* __restrict__ U,
                                                  const float* __restrict__ x,
                                                  const float* __restrict__ bias,
                                                  const float* __restrict__ c0,
                                                  float* __restrict__ h,
                                                  float* __restrict__ clast) {
  __shared__ float sA[NCHUNK][64];
  __shared__ float sB[NCHUNK][64];
  __shared__ float sC[NCHUNK][64];

  const int flat = blockIdx.x;                     // 0..255
  const int cb = (flat & 7) * 32 + (flat >> 3);    // chain-block 0..255
  const int b  = cb >> 4;                          // batch 0..15
  const int d0 = (cb & 15) << 6;                   // d base, step 64
  const int t  = threadIdx.x;
  const int q  = t & 15;                           // quad 0..15 (4 chains)
  const int j  = t >> 4;                           // chunk 0..63
  const int d4 = d0 + q * 4;

  const float4 bb1 = *(const float4*)(bias + d4);

  // ---- phase A: per-(chunk, 4-chain) affine composition ----
  {
    const u16* p = U + (size_t)(j * CHUNK * B_DIM + b) * N_DIM + d4;
    float A0 = 1.0f, A1 = 1.0f, A2 = 1.0f, A3 = 1.0f;
    float B0 = 0.0f, B1 = 0.0f, B2 = 0.0f, B3 = 0.0f;
#pragma unroll 4
    for (int s = 0; s < CHUNK; ++s) {
      uint2 w0 = *(const uint2*)p;
      uint2 w1 = *(const uint2*)(p + D_DIM);
      float u00 = bf2f_lo(w0.x), u01 = bf2f_hi(w0.x);
      float u02 = bf2f_lo(w0.y), u03 = bf2f_hi(w0.y);
      float g10 = sigm(bf2f_lo(w1.x) + bb1.x);
      float g11 = sigm(bf2f_hi(w1.x) + bb1.y);
      float g12 = sigm(bf2f_lo(w1.y) + bb1.z);
      float g13 = sigm(bf2f_hi(w1.y) + bb1.w);
      B0 = (B0 - u00) * g10 + u00;  A0 *= g10;
      B1 = (B1 - u01) * g11 + u01;  A1 *= g11;
      B2 = (B2 - u02) * g12 + u02;  A2 *= g12;
      B3 = (B3 - u03) * g13 + u03;  A3 *= g13;
      p += (size_t)B_DIM * N_DIM;
    }
    *(float4*)&sA[j][q * 4] = make_float4(A0, A1, A2, A3);
    *(float4*)&sB[j][q * 4] = make_float4(B0, B1, B2, B3);
  }
  __syncthreads();

  // ---- phase B: serial scan over 64 chunks, one lane per chain ----
  if (t < 64) {
    const int chain = cb * 64 + t;   // = b*D + d0 + t
    float c = c0[chain];
#pragma unroll
    for (int jj = 0; jj < NCHUNK; ++jj) {
      sC[jj][t] = c;
      c = sA[jj][t] * c + sB[jj][t];
    }
    clast[chain] = c;
  }
  __syncthreads();

  // ---- phase C: replay with h output ----
  {
    const float4 bb2 = *(const float4*)(bias + D_DIM + d4);
    float4 c = *(const float4*)&sC[j][q * 4];
    const size_t m0 = (size_t)(j * CHUNK * B_DIM + b);
    const u16* p = U + m0 * N_DIM + d4;
    const float* xp = x + m0 * D_DIM + d4;
    float* hp = h + m0 * D_DIM + d4;
#pragma unroll 4
    for (int s = 0; s < CHUNK; ++s) {
      uint2 w0 = *(const uint2*)p;
      uint2 w1 = *(const uint2*)(p + D_DIM);
      uint2 w2 = *(const uint2*)(p + 2 * D_DIM);
      float4 xv = *(const float4*)xp;
      float u00 = bf2f_lo(w0.x), u01 = bf2f_hi(w0.x);
      float u02 = bf2f_lo(w0.y), u03 = bf2f_hi(w0.y);
      float g10 = sigm(bf2f_lo(w1.x) + bb1.x);
      float g11 = sigm(bf2f_hi(w1.x) + bb1.y);
      float g12 = sigm(bf2f_lo(w1.y) + bb1.z);
      float g13 = sigm(bf2f_hi(w1.y) + bb1.w);
      float g20 = sigm(bf2f_lo(w2.x) + bb2.x);
      float g21 = sigm(bf2f_hi(w2.x) + bb2.y);
      float g22 = sigm(bf2f_lo(w2.y) + bb2.z);
      float g23 = sigm(bf2f_hi(w2.y) + bb2.w);
      c.x = (c.x - u00) * g10 + u00;
      c.y = (c.y - u01) * g11 + u01;
      c.z = (c.z - u02) * g12 + u02;
      c.w = (c.w - u03) * g13 + u03;
      float4 hv;
      hv.x = (ftanh(c.x) - xv.x) * g20 + xv.x;
      hv.y = (ftanh(c.y) - xv.y) * g21 + xv.y;
      hv.z = (ftanh(c.z) - xv.z) * g22 + xv.z;
      hv.w = (ftanh(c.w) - xv.w) * g23 + xv.w;
      *(float4*)hp = hv;
      p += (size_t)B_DIM * N_DIM;
      xp += B_DIM * D_DIM;
      hp += B_DIM * D_DIM;
    }
  }
}

extern "C" void kernel_launch(void* const* d_in, const int* in_sizes, int n_in,
                              void* d_out, int out_size, void* d_ws, size_t ws_size,
                              hipStream_t stream) {
  const float* x = (const float*)d_in[0];     // L*B*D
  const float* W = (const float*)d_in[1];     // K x 3D
  const float* bias = (const float*)d_in[2];  // 2D
  const float* c0 = (const float*)d_in[3];    // B*D
  float* out = (float*)d_out;

  char* ws = (char*)d_ws;
  u16* xb = (u16*)ws;                               // 32 MiB
  u16* wt = (u16*)(ws + 33554432);                  // 6 MiB
  u16* U = (u16*)(ws + 33554432 + 6291456);         // 96 MiB

  cvt_x_kernel<<<16384, 256, 0, stream>>>((const float4*)x, (ushort4*)xb, M_DIM * K_DIM / 4);
  cvt_w_kernel<<<dim3(48, 16), 256, 0, stream>>>(W, wt);
  gemm_kernel<<<dim3(N_DIM / 256, M_DIM / 256), 512, 0, stream>>>(xb, wt, U);
  sru_fused<<<256, 1024, 0, stream>>>(U, x, bias, c0, out, out + (size_t)M_DIM * D_DIM);
}